// Round 9
// baseline (282.873 us; speedup 1.0000x reference)
//
#include <hip/hip_runtime.h>

// Shapes (fixed): B=4, D=8, H=14, W=14, C=768, NH=12, hd=64, N=1568 (pad 1600), BH=48, M=6272

typedef __bf16 bf16x8 __attribute__((ext_vector_type(8)));
typedef float f32x4 __attribute__((ext_vector_type(4)));

#define MFMA16(a, b, c) __builtin_amdgcn_mfma_f32_16x16x32_bf16((a), (b), (c), 0, 0, 0)

#if __has_builtin(__builtin_amdgcn_exp2f)
#define EXP2(x) __builtin_amdgcn_exp2f(x)
#else
#define EXP2(x) exp2f(x)
#endif

static __device__ __forceinline__ unsigned short f2bf(float f) {
    union { float f; unsigned int u; } v; v.f = f;
    unsigned int u = v.u;
    return (unsigned short)((u + 0x7fffu + ((u >> 16) & 1u)) >> 16);
}

static __device__ __forceinline__ bf16x8 ld_bf8(const unsigned short* p) {
    return *reinterpret_cast<const bf16x8*>(p);
}

// async global->LDS DMA, 16 B per lane; lds dest = wave-uniform base + lane*16
static __device__ __forceinline__ void dma16(const void* g, void* l) {
    __builtin_amdgcn_global_load_lds(
        (const __attribute__((address_space(1))) void*)g,
        (__attribute__((address_space(3))) void*)l, 16, 0, 0);
}

// ---------------- prep kernels ----------------

__global__ void k_cvt_x(const float* __restrict__ x, unsigned short* __restrict__ xbf, int n4) {
    int i = blockIdx.x * blockDim.x + threadIdx.x;
    if (i < n4) {
        float4 v = reinterpret_cast<const float4*>(x)[i];
        ushort4 o;
        o.x = f2bf(v.x); o.y = f2bf(v.y); o.z = f2bf(v.z); o.w = f2bf(v.w);
        reinterpret_cast<ushort4*>(xbf)[i] = o;
    }
}

// w [K][N] fp32 -> wt [N][K] bf16 ; K,N multiples of 64
__global__ __launch_bounds__(256) void k_transpose(const float* __restrict__ w,
                                                   unsigned short* __restrict__ wt,
                                                   int K, int N) {
    __shared__ float tile[64][65];
    int kt = blockIdx.x * 64;
    int nt = blockIdx.y * 64;
    int tid = threadIdx.x;
    int r = tid >> 2;
    int cg = tid & 3;
#pragma unroll
    for (int i = 0; i < 4; ++i) {
        int c = cg * 16 + i * 4;
        float4 v = *reinterpret_cast<const float4*>(&w[(size_t)(kt + r) * N + nt + c]);
        tile[r][c + 0] = v.x; tile[r][c + 1] = v.y; tile[r][c + 2] = v.z; tile[r][c + 3] = v.w;
    }
    __syncthreads();
#pragma unroll
    for (int i = 0; i < 4; ++i) {
        int c = cg * 16 + i * 4;
        ushort4 o;
        o.x = f2bf(tile[c + 0][r]);
        o.y = f2bf(tile[c + 1][r]);
        o.z = f2bf(tile[c + 2][r]);
        o.w = f2bf(tile[c + 3][r]);
        *reinterpret_cast<ushort4*>(&wt[(size_t)(nt + r) * K + kt + c]) = o;
    }
}

// concat rel_pos tables, PRE-SCALED by log2(e) (softmax runs in exp2 domain)
__global__ void k_tables(const float* __restrict__ rd, const float* __restrict__ rh,
                         const float* __restrict__ rw, unsigned short* __restrict__ T) {
    int i = blockIdx.x * blockDim.x + threadIdx.x;
    if (i < 80 * 64) {
        int row = i >> 6, c = i & 63;
        float v = 0.f;
        if (row < 15) v = rd[row * 64 + c];
        else if (row < 42) v = rh[(row - 15) * 64 + c];
        else if (row < 69) v = rw[(row - 42) * 64 + c];
        T[i] = f2bf(v * 1.44269504f);
    }
}

// indicator table ind[1600][64]: key<1568: one-hot kd@0..7, kh@8..21, kw@22..35;
// key>=1568: 1.0 @ 36 (pairs with Q-side -30000 -> exp2->0 masks the pad keys)
__global__ void k_fill_ind(unsigned short* __restrict__ indb) {
    int i = blockIdx.x * blockDim.x + threadIdx.x;
    if (i < 1600 * 64) {
        int key = i >> 6, c = i & 63;
        unsigned short v = 0;
        if (key < 1568) {
            int kd = key / 196;
            int r = key - kd * 196;
            int kh = r / 14;
            int kw = r - kh * 14;
            if (c == kd || c == 8 + kh || c == 22 + kw) v = 0x3F80;  // bf16 1.0
        } else {
            if (c == 36) v = 0x3F80;
        }
        indb[i] = v;
    }
}

// ---------------- shared GEMM core: LDS-staged 128x128 tile, BK=64, K=768 ----------------
static __device__ __forceinline__ void gemm_core(const unsigned short* __restrict__ A,
                                                 const unsigned short* __restrict__ B,
                                                 int M_base, int N_base,
                                                 char* smem, f32x4 acc[4][4]) {
    const int lane = threadIdx.x & 63;
    const int wid = threadIdx.x >> 6;
    const int ww = wid & 1, wh = wid >> 1;
    const int quad = lane >> 4, l16 = lane & 15;
    const int sr = lane >> 3, sc = lane & 7;
    unsigned short* sA = (unsigned short*)smem;
    unsigned short* sB = (unsigned short*)(smem + 16384);

    for (int kt = 0; kt < 12; ++kt) {
#pragma unroll
        for (int j = 0; j < 4; ++j) {
            int loc = wid * 32 + j * 8 + sr;
            int gc = ((sc + loc) & 7) * 16;
            dma16((const char*)A + (size_t)(M_base + loc) * 1536 + kt * 128 + gc,
                  (char*)sA + (wid * 32 + j * 8) * 128);
            dma16((const char*)B + (size_t)(N_base + loc) * 1536 + kt * 128 + gc,
                  (char*)sB + (wid * 32 + j * 8) * 128);
        }
        __syncthreads();
#pragma unroll
        for (int s = 0; s < 2; ++s) {
            bf16x8 af[4], bfr[4];
#pragma unroll
            for (int i = 0; i < 4; ++i) {
                int ar = wh * 64 + i * 16 + l16;
                af[i] = ld_bf8(sA + ar * 64 + (((s * 4 + quad) - ar) & 7) * 8);
                int br = ww * 64 + i * 16 + l16;
                bfr[i] = ld_bf8(sB + br * 64 + (((s * 4 + quad) - br) & 7) * 8);
            }
#pragma unroll
            for (int i = 0; i < 4; ++i)
#pragma unroll
                for (int j2 = 0; j2 < 4; ++j2)
                    acc[i][j2] = MFMA16(af[i], bfr[j2], acc[i][j2]);
        }
        __syncthreads();
    }
}

// ---------------- GEMM1: qkv = x @ qkv_w + b -> q, k(scaled 0.125*log2e), v(natural) ----------------
__global__ __launch_bounds__(256, 4) void k_qkv(const unsigned short* __restrict__ xbf,
                                                const unsigned short* __restrict__ w1t,
                                                const float* __restrict__ qkv_b,
                                                unsigned short* __restrict__ qb,
                                                unsigned short* __restrict__ kb2,
                                                unsigned short* __restrict__ vb) {
    __shared__ __align__(16) char smem[32768];
    f32x4 acc[4][4] = {};
    gemm_core(xbf, w1t, blockIdx.x * 128, blockIdx.y * 128, smem, acc);

    const int lane = threadIdx.x & 63;
    const int wid = threadIdx.x >> 6;
    const int ww = wid & 1, wh = wid >> 1;
    const int quad = lane >> 4, l16 = lane & 15;
#pragma unroll
    for (int j = 0; j < 4; ++j) {
        int n = blockIdx.y * 128 + ww * 64 + j * 16 + l16;
        float bias = qkv_b[n];
        int which = n / 768;
        int rem = n - which * 768;
        int head = rem >> 6;
        int c = rem & 63;
#pragma unroll
        for (int i = 0; i < 4; ++i) {
#pragma unroll
            for (int r = 0; r < 4; ++r) {
                int m = blockIdx.x * 128 + wh * 64 + i * 16 + quad * 4 + r;
                float val = acc[i][j][r] + bias;
                int b_ = m / 1568;
                int nn = m - b_ * 1568;
                size_t idx = ((size_t)(b_ * 12 + head) * 1568 + nn) * 64 + c;
                if (which == 0)      qb[idx] = f2bf(val);
                else if (which == 1) kb2[(((size_t)(b_ * 12 + head)) * 1600 + nn) * 64 + c] = f2bf(val * 0.18033688f);
                else                 vb[idx] = f2bf(val);
            }
        }
    }
}

// v [48][1568][64] -> vtb [48][64][1600]
__global__ __launch_bounds__(256) void k_vt(const unsigned short* __restrict__ vb,
                                            unsigned short* __restrict__ vtb) {
    __shared__ unsigned short t[64][72];
    int bh = blockIdx.y;
    int n0 = blockIdx.x * 64;
    int tid = threadIdx.x;
    int r = tid >> 2, cg = (tid & 3) * 16;
    int n = n0 + r;
    if (n > 1567) n = 1567;
    const unsigned short* src = vb + ((size_t)bh * 1568 + n) * 64 + cg;
    *reinterpret_cast<uint4*>(&t[r][cg]) = *reinterpret_cast<const uint4*>(src);
    *reinterpret_cast<uint4*>(&t[r][cg + 8]) = *reinterpret_cast<const uint4*>(src + 8);
    __syncthreads();
    int c = tid >> 2, ng = (tid & 3) * 16;
    if (n0 + ng < 1568) {
        unsigned short buf[16];
#pragma unroll
        for (int i = 0; i < 16; ++i) buf[i] = t[ng + i][c];
        unsigned short* dst = vtb + ((size_t)bh * 64 + c) * 1600 + n0 + ng;
        *reinterpret_cast<uint4*>(dst) = *reinterpret_cast<uint4*>(&buf[0]);
        *reinterpret_cast<uint4*>(dst + 8) = *reinterpret_cast<uint4*>(&buf[8]);
    }
}

// ---------------- attention: double-buffered K/V staging; ind register-pipelined ----------------
// grid (48 bh, 13 qt); block 256 = 4 waves x 32 q-rows. Softmax in exp2 domain.
// LDS: buf0 @0 (16384 = K 8K | V 8K), buf1 @16384, pP @32768 (4 x 2304) = 41984 -> 3 blocks/CU.
// ind frags for kt are loaded into registers during iteration kt-1 (BEFORE that iteration's
// stage DMAs would matter): the end-of-iter barrier drains them, so S-MFMA starts with no
// vmcnt wait and never forces the in-flight prefetch DMAs to retire early.
__global__ __launch_bounds__(256, 3) void k_attn(const unsigned short* __restrict__ qb,
                                                 const unsigned short* __restrict__ kb2,
                                                 const unsigned short* __restrict__ indb,
                                                 const unsigned short* __restrict__ vtb,
                                                 const unsigned short* __restrict__ Tbf,
                                                 unsigned short* __restrict__ obf) {
    __shared__ __align__(16) char smem[41984];
    const int lane = threadIdx.x & 63;
    const int wid = threadIdx.x >> 6;
    const int quad = lane >> 4;
    const int l16 = lane & 15;
    const int sr = lane >> 3;
    const int sc = lane & 7;
    const int bh = blockIdx.x;
    const int qt = blockIdx.y;

    unsigned short* pw = (unsigned short*)(smem + 32768 + wid * 2304);  // per-wave P [16][72]
    unsigned short* tR = (unsigned short*)(smem + wid * 5120);          // transient qR [32][80]
    unsigned short* tB = (unsigned short*)(smem + 20480 + wid * 4608);  // transient qbx [32][72]

    // ---- prologue: Q frags, qR = q.T^T (log2e-scaled), extended-Q bias frags ----
    bf16x8 a_q0[2], a_q1[2], a_b0[2], a_b1[2];
#pragma unroll
    for (int mt = 0; mt < 2; ++mt) {
        int qrow = qt * 128 + wid * 32 + mt * 16 + l16;
        if (qrow > 1567) qrow = 1567;
        const unsigned short* qp = qb + ((size_t)bh * 1568 + qrow) * 64 + quad * 8;
        a_q0[mt] = ld_bf8(qp);
        a_q1[mt] = ld_bf8(qp + 32);
    }
#pragma unroll
    for (int mt = 0; mt < 2; ++mt) {
#pragma unroll
        for (int ng = 0; ng < 5; ++ng) {
            const unsigned short* tp = Tbf + (size_t)(ng * 16 + l16) * 64 + quad * 8;
            f32x4 t = {};
            t = MFMA16(a_q0[mt], ld_bf8(tp), t);
            t = MFMA16(a_q1[mt], ld_bf8(tp + 32), t);
#pragma unroll
            for (int r = 0; r < 4; ++r)
                tR[(mt * 16 + quad * 4 + r) * 80 + ng * 16 + l16] = f2bf(t[r]);
        }
    }
#pragma unroll
    for (int mt = 0; mt < 2; ++mt) {
        int gq = qt * 128 + wid * 32 + mt * 16 + l16;
        if (gq > 1567) gq = 1567;
        int qd = gq / 196;
        int rm = gq - qd * 196;
        int qh = rm / 14;
        int qw = rm - qh * 14;
        const unsigned short* qr = tR + (mt * 16 + l16) * 80;
        unsigned short* qxr = tB + (mt * 16 + l16) * 72;
#pragma unroll
        for (int t = 0; t < 16; ++t) {
            int dd = quad * 16 + t;
            unsigned short v = 0;
            if (dd < 8)        v = qr[qd - dd + 7];
            else if (dd < 22)  v = qr[15 + qh - (dd - 8) + 13];
            else if (dd < 36)  v = qr[42 + qw - (dd - 22) + 13];
            else if (dd == 36) v = 0xC6EA;  // bf16(-30000): exp2 -> 0 pad-key mask
            qxr[dd] = v;
        }
    }
#pragma unroll
    for (int mt = 0; mt < 2; ++mt) {
        const unsigned short* qx = tB + (mt * 16 + l16) * 72;
        a_b0[mt] = ld_bf8(qx + quad * 8);
        a_b1[mt] = ld_bf8(qx + 32 + quad * 8);
    }
    // CROSS-WAVE hazard: stage() below overwrites other waves' tR/tB regions.
    __syncthreads();

    const char* kbh_b = (const char*)(kb2 + (size_t)bh * 1600 * 64);
    const char* vbh_b = (const char*)(vtb + (size_t)bh * 64 * 1600);

    // DMA stage a 64-key tile into buffer sbase (K | V regions; ind NOT staged)
    auto stage = [&](char* sbase, int kb0) {
#pragma unroll
        for (int j = 0; j < 2; ++j) {
            int loc = wid * 16 + j * 8 + sr;
            int gc = ((sc + loc) & 7) * 16;
            char* d = sbase + (wid * 16 + j * 8) * 128;
            dma16(kbh_b + (size_t)(kb0 + loc) * 128 + gc, d);
            dma16(vbh_b + (size_t)loc * 3200 + (size_t)kb0 * 2 + gc, d + 8192);
        }
    };
    // ind fragment loads (wave-invariant addresses; register double-buffer)
    auto ld_ind = [&](int kb0, bf16x8* i0, bf16x8* i1) {
#pragma unroll
        for (int kg = 0; kg < 4; ++kg) {
            const unsigned short* ir = indb + (size_t)(kb0 + kg * 16 + l16) * 64 + quad * 8;
            i0[kg] = ld_bf8(ir);
            i1[kg] = ld_bf8(ir + 32);
        }
    };

    float l_p[2][4] = {};   // per-lane partial rowsums (reduced once at the end)
    f32x4 Oacc[2][4] = {};
    bf16x8 ni0[4], ni1[4], xi0[4], xi1[4];

    ld_ind(0, ni0, ni1);
    stage(smem, 0);
    __syncthreads();   // drains DMA + ind loads for kt=0

    for (int kt = 0; kt < 25; ++kt) {
        char* cur = smem + (kt & 1) * 16384;
        if (kt < 24) {
            ld_ind((kt + 1) * 64, xi0, xi1);          // prefetch ind frags (registers)
            stage(smem + ((kt + 1) & 1) * 16384, (kt + 1) * 64);  // prefetch K/V tile (LDS DMA)
        }

        const unsigned short* sK = (const unsigned short*)cur;
        const unsigned short* sV = (const unsigned short*)(cur + 8192);

        // ---- S = [q|qbias].[k*0.125*log2e|ind], exp2, partial rowsum ----
        float p[2][4][4];
#pragma unroll
        for (int kg = 0; kg < 4; ++kg) {
            int key = kg * 16 + l16;
            const unsigned short* kr = sK + key * 64;
            bf16x8 bk0 = ld_bf8(kr + ((quad - key) & 7) * 8);
            bf16x8 bk1 = ld_bf8(kr + ((quad + 4 - key) & 7) * 8);
#pragma unroll
            for (int mt = 0; mt < 2; ++mt) {
                f32x4 t = {};
                t = MFMA16(a_q0[mt], bk0, t);
                t = MFMA16(a_q1[mt], bk1, t);
                t = MFMA16(a_b0[mt], ni0[kg], t);
                t = MFMA16(a_b1[mt], ni1[kg], t);
#pragma unroll
                for (int r = 0; r < 4; ++r) {
                    union { float f; unsigned int u; } c;
                    c.f = EXP2(t[r]);
                    c.u &= 0xFFFF0000u;       // truncate to bf16-representable (consistent num/denom)
                    p[mt][kg][r] = c.f;
                    l_p[mt][r] += c.f;
                }
            }
        }
        // ---- V frags into registers (shared across both m-tiles) ----
        bf16x8 v0[4], v1[4];
#pragma unroll
        for (int cg = 0; cg < 4; ++cg) {
            int dim = cg * 16 + l16;
            const unsigned short* vr = sV + dim * 64;
            v0[cg] = ld_bf8(vr + ((quad - dim) & 7) * 8);
            v1[cg] = ld_bf8(vr + ((quad + 4 - dim) & 7) * 8);
        }
        // ---- per-mt: P C->A transform via wave-private LDS, then PV ----
#pragma unroll
        for (int mt = 0; mt < 2; ++mt) {
#pragma unroll
            for (int kg = 0; kg < 4; ++kg)
#pragma unroll
                for (int r = 0; r < 4; ++r) {
                    union { float f; unsigned int u; } c;
                    c.f = p[mt][kg][r];
                    pw[(quad * 4 + r) * 72 + kg * 16 + l16] = (unsigned short)(c.u >> 16);
                }
            const unsigned short* pr = pw + l16 * 72;
            bf16x8 ap0 = ld_bf8(pr + quad * 8);
            bf16x8 ap1 = ld_bf8(pr + 32 + quad * 8);
#pragma unroll
            for (int cg = 0; cg < 4; ++cg) {
                Oacc[mt][cg] = MFMA16(ap0, v0[cg], Oacc[mt][cg]);
                Oacc[mt][cg] = MFMA16(ap1, v1[cg], Oacc[mt][cg]);
            }
        }
        __syncthreads();  // cur consumed; drains next tile's DMA + ind loads
#pragma unroll
        for (int kg = 0; kg < 4; ++kg) { ni0[kg] = xi0[kg]; ni1[kg] = xi1[kg]; }
    }

    // ---- final rowsum reduce + epilogue ----
    int b_ = bh / 12;
    int head = bh - b_ * 12;
    unsigned short* ob = obf + (size_t)b_ * 1568 * 768 + head * 64;
#pragma unroll
    for (int mt = 0; mt < 2; ++mt)
#pragma unroll
        for (int r = 0; r < 4; ++r) {
            float v = l_p[mt][r];
            v += __shfl_xor(v, 1);
            v += __shfl_xor(v, 2);
            v += __shfl_xor(v, 4);
            v += __shfl_xor(v, 8);
            int gq = qt * 128 + wid * 32 + mt * 16 + quad * 4 + r;
            if (gq < 1568) {
                float inv = 1.0f / v;
#pragma unroll
                for (int cg = 0; cg < 4; ++cg)
                    ob[(size_t)gq * 768 + cg * 16 + l16] = f2bf(Oacc[mt][cg][r] * inv);
            }
        }
}

// ---------------- GEMM3: out = O @ proj_w + proj_b (fp32 out), LDS-staged ----------------
__global__ __launch_bounds__(256, 3) void k_proj(const unsigned short* __restrict__ obf,
                                                 const unsigned short* __restrict__ w2t,
                                                 const float* __restrict__ proj_b,
                                                 float* __restrict__ out) {
    __shared__ __align__(16) char smem[32768];
    f32x4 acc[4][4] = {};
    gemm_core(obf, w2t, blockIdx.x * 128, blockIdx.y * 128, smem, acc);

    const int lane = threadIdx.x & 63;
    const int wid = threadIdx.x >> 6;
    const int ww = wid & 1, wh = wid >> 1;
    const int quad = lane >> 4, l16 = lane & 15;
#pragma unroll
    for (int j = 0; j < 4; ++j) {
        int n = blockIdx.y * 128 + ww * 64 + j * 16 + l16;
        float bias = proj_b[n];
#pragma unroll
        for (int i = 0; i < 4; ++i) {
#pragma unroll
            for (int r = 0; r < 4; ++r) {
                int m = blockIdx.x * 128 + wh * 64 + i * 16 + quad * 4 + r;
                out[(size_t)m * 768 + n] = acc[i][j][r] + bias;
            }
        }
    }
}

// ---------------- launch ----------------
extern "C" void kernel_launch(void* const* d_in, const int* in_sizes, int n_in,
                              void* d_out, int out_size, void* d_ws, size_t ws_size,
                              hipStream_t stream) {
    const float* x      = (const float*)d_in[0];
    const float* qkv_w  = (const float*)d_in[1];
    const float* qkv_b  = (const float*)d_in[2];
    const float* proj_w = (const float*)d_in[3];
    const float* proj_b = (const float*)d_in[4];
    const float* rd     = (const float*)d_in[5];
    const float* rh     = (const float*)d_in[6];
    const float* rw     = (const float*)d_in[7];
    float* out = (float*)d_out;

    char* ws = (char*)d_ws;
    size_t off = 0;
    auto alloc = [&](size_t bytes) {
        char* p = ws + off;
        off += (bytes + 255) & ~(size_t)255;
        return p;
    };
    unsigned short* xbf  = (unsigned short*)alloc((size_t)6272 * 768 * 2);   // reused as obf
    unsigned short* w1t  = (unsigned short*)alloc((size_t)2304 * 768 * 2);
    unsigned short* w2t  = (unsigned short*)alloc((size_t)768 * 768 * 2);
    unsigned short* Tbf  = (unsigned short*)alloc((size_t)80 * 64 * 2);
    unsigned short* qb   = (unsigned short*)alloc((size_t)48 * 1568 * 64 * 2);
    unsigned short* kb2  = (unsigned short*)alloc((size_t)48 * 1600 * 64 * 2);
    unsigned short* vtb  = (unsigned short*)alloc((size_t)48 * 64 * 1600 * 2);
    unsigned short* indb = (unsigned short*)alloc((size_t)1600 * 64 * 2);
    unsigned short* obf  = xbf;                 // x dead after k_qkv
    unsigned short* vb   = (unsigned short*)d_out;  // d_out as scratch: k_proj overwrites it last

    hipLaunchKernelGGL(k_cvt_x, dim3(4704), dim3(256), 0, stream, x, xbf, 1204224);
    hipLaunchKernelGGL(k_transpose, dim3(12, 36), dim3(256), 0, stream, qkv_w, w1t, 768, 2304);
    hipLaunchKernelGGL(k_transpose, dim3(12, 12), dim3(256), 0, stream, proj_w, w2t, 768, 768);
    hipLaunchKernelGGL(k_tables, dim3(20), dim3(256), 0, stream, rd, rh, rw, Tbf);
    hipLaunchKernelGGL(k_fill_ind, dim3(400), dim3(256), 0, stream, indb);
    hipLaunchKernelGGL(k_qkv, dim3(49, 18), dim3(256), 0, stream, xbf, w1t, qkv_b, qb, kb2, vb);
    hipLaunchKernelGGL(k_vt, dim3(25, 48), dim3(256), 0, stream, vb, vtb);
    hipLaunchKernelGGL(k_attn, dim3(48, 13), dim3(256), 0, stream, qb, kb2, indb, vtb, Tbf, obf);
    hipLaunchKernelGGL(k_proj, dim3(49, 6), dim3(256), 0, stream, obf, w2t, proj_b, out);
}

// Round 10
// 237.329 us; speedup vs baseline: 1.1919x; 1.1919x over previous
//
#include <hip/hip_runtime.h>

// Shapes (fixed): B=4, D=8, H=14, W=14, C=768, NH=12, hd=64, N=1568 (pad 1600), BH=48, M=6272

typedef __bf16 bf16x8 __attribute__((ext_vector_type(8)));
typedef float f32x4 __attribute__((ext_vector_type(4)));

#define MFMA16(a, b, c) __builtin_amdgcn_mfma_f32_16x16x32_bf16((a), (b), (c), 0, 0, 0)

#if __has_builtin(__builtin_amdgcn_exp2f)
#define EXP2(x) __builtin_amdgcn_exp2f(x)
#else
#define EXP2(x) exp2f(x)
#endif

static __device__ __forceinline__ unsigned short f2bf(float f) {
    union { float f; unsigned int u; } v; v.f = f;
    unsigned int u = v.u;
    return (unsigned short)((u + 0x7fffu + ((u >> 16) & 1u)) >> 16);
}

static __device__ __forceinline__ bf16x8 ld_bf8(const unsigned short* p) {
    return *reinterpret_cast<const bf16x8*>(p);
}

// async global->LDS DMA, 16 B per lane; lds dest = wave-uniform base + lane*16
static __device__ __forceinline__ void dma16(const void* g, void* l) {
    __builtin_amdgcn_global_load_lds(
        (const __attribute__((address_space(1))) void*)g,
        (__attribute__((address_space(3))) void*)l, 16, 0, 0);
}

// ---------------- prep kernels ----------------

__global__ void k_cvt_x(const float* __restrict__ x, unsigned short* __restrict__ xbf, int n4) {
    int i = blockIdx.x * blockDim.x + threadIdx.x;
    if (i < n4) {
        float4 v = reinterpret_cast<const float4*>(x)[i];
        ushort4 o;
        o.x = f2bf(v.x); o.y = f2bf(v.y); o.z = f2bf(v.z); o.w = f2bf(v.w);
        reinterpret_cast<ushort4*>(xbf)[i] = o;
    }
}

// w [K][N] fp32 -> wt [N][K] bf16 ; K,N multiples of 64
__global__ __launch_bounds__(256) void k_transpose(const float* __restrict__ w,
                                                   unsigned short* __restrict__ wt,
                                                   int K, int N) {
    __shared__ float tile[64][65];
    int kt = blockIdx.x * 64;
    int nt = blockIdx.y * 64;
    int tid = threadIdx.x;
    int r = tid >> 2;
    int cg = tid & 3;
#pragma unroll
    for (int i = 0; i < 4; ++i) {
        int c = cg * 16 + i * 4;
        float4 v = *reinterpret_cast<const float4*>(&w[(size_t)(kt + r) * N + nt + c]);
        tile[r][c + 0] = v.x; tile[r][c + 1] = v.y; tile[r][c + 2] = v.z; tile[r][c + 3] = v.w;
    }
    __syncthreads();
#pragma unroll
    for (int i = 0; i < 4; ++i) {
        int c = cg * 16 + i * 4;
        ushort4 o;
        o.x = f2bf(tile[c + 0][r]);
        o.y = f2bf(tile[c + 1][r]);
        o.z = f2bf(tile[c + 2][r]);
        o.w = f2bf(tile[c + 3][r]);
        *reinterpret_cast<ushort4*>(&wt[(size_t)(nt + r) * K + kt + c]) = o;
    }
}

// concat rel_pos tables, PRE-SCALED by log2(e) (softmax runs in exp2 domain)
__global__ void k_tables(const float* __restrict__ rd, const float* __restrict__ rh,
                         const float* __restrict__ rw, unsigned short* __restrict__ T) {
    int i = blockIdx.x * blockDim.x + threadIdx.x;
    if (i < 80 * 64) {
        int row = i >> 6, c = i & 63;
        float v = 0.f;
        if (row < 15) v = rd[row * 64 + c];
        else if (row < 42) v = rh[(row - 15) * 64 + c];
        else if (row < 69) v = rw[(row - 42) * 64 + c];
        T[i] = f2bf(v * 1.44269504f);
    }
}

// indicator table ind[1600][64]: key<1568: one-hot kd@0..7, kh@8..21, kw@22..35;
// key>=1568: 1.0 @ 36 (pairs with Q-side -30000 -> exp2->0 masks the pad keys)
__global__ void k_fill_ind(unsigned short* __restrict__ indb) {
    int i = blockIdx.x * blockDim.x + threadIdx.x;
    if (i < 1600 * 64) {
        int key = i >> 6, c = i & 63;
        unsigned short v = 0;
        if (key < 1568) {
            int kd = key / 196;
            int r = key - kd * 196;
            int kh = r / 14;
            int kw = r - kh * 14;
            if (c == kd || c == 8 + kh || c == 22 + kw) v = 0x3F80;  // bf16 1.0
        } else {
            if (c == 36) v = 0x3F80;
        }
        indb[i] = v;
    }
}

// ---------------- shared GEMM core: LDS-staged 128x128 tile, BK=64, K=768 ----------------
static __device__ __forceinline__ void gemm_core(const unsigned short* __restrict__ A,
                                                 const unsigned short* __restrict__ B,
                                                 int M_base, int N_base,
                                                 char* smem, f32x4 acc[4][4]) {
    const int lane = threadIdx.x & 63;
    const int wid = threadIdx.x >> 6;
    const int ww = wid & 1, wh = wid >> 1;
    const int quad = lane >> 4, l16 = lane & 15;
    const int sr = lane >> 3, sc = lane & 7;
    unsigned short* sA = (unsigned short*)smem;
    unsigned short* sB = (unsigned short*)(smem + 16384);

    for (int kt = 0; kt < 12; ++kt) {
#pragma unroll
        for (int j = 0; j < 4; ++j) {
            int loc = wid * 32 + j * 8 + sr;
            int gc = ((sc + loc) & 7) * 16;
            dma16((const char*)A + (size_t)(M_base + loc) * 1536 + kt * 128 + gc,
                  (char*)sA + (wid * 32 + j * 8) * 128);
            dma16((const char*)B + (size_t)(N_base + loc) * 1536 + kt * 128 + gc,
                  (char*)sB + (wid * 32 + j * 8) * 128);
        }
        __syncthreads();
#pragma unroll
        for (int s = 0; s < 2; ++s) {
            bf16x8 af[4], bfr[4];
#pragma unroll
            for (int i = 0; i < 4; ++i) {
                int ar = wh * 64 + i * 16 + l16;
                af[i] = ld_bf8(sA + ar * 64 + (((s * 4 + quad) - ar) & 7) * 8);
                int br = ww * 64 + i * 16 + l16;
                bfr[i] = ld_bf8(sB + br * 64 + (((s * 4 + quad) - br) & 7) * 8);
            }
#pragma unroll
            for (int i = 0; i < 4; ++i)
#pragma unroll
                for (int j2 = 0; j2 < 4; ++j2)
                    acc[i][j2] = MFMA16(af[i], bfr[j2], acc[i][j2]);
        }
        __syncthreads();
    }
}

// ---------------- GEMM1: qkv = x @ qkv_w + b -> q, k(scaled 0.125*log2e), v(natural) ----------------
__global__ __launch_bounds__(256, 4) void k_qkv(const unsigned short* __restrict__ xbf,
                                                const unsigned short* __restrict__ w1t,
                                                const float* __restrict__ qkv_b,
                                                unsigned short* __restrict__ qb,
                                                unsigned short* __restrict__ kb2,
                                                unsigned short* __restrict__ vb) {
    __shared__ __align__(16) char smem[32768];
    f32x4 acc[4][4] = {};
    gemm_core(xbf, w1t, blockIdx.x * 128, blockIdx.y * 128, smem, acc);

    const int lane = threadIdx.x & 63;
    const int wid = threadIdx.x >> 6;
    const int ww = wid & 1, wh = wid >> 1;
    const int quad = lane >> 4, l16 = lane & 15;
#pragma unroll
    for (int j = 0; j < 4; ++j) {
        int n = blockIdx.y * 128 + ww * 64 + j * 16 + l16;
        float bias = qkv_b[n];
        int which = n / 768;
        int rem = n - which * 768;
        int head = rem >> 6;
        int c = rem & 63;
#pragma unroll
        for (int i = 0; i < 4; ++i) {
#pragma unroll
            for (int r = 0; r < 4; ++r) {
                int m = blockIdx.x * 128 + wh * 64 + i * 16 + quad * 4 + r;
                float val = acc[i][j][r] + bias;
                int b_ = m / 1568;
                int nn = m - b_ * 1568;
                size_t idx = ((size_t)(b_ * 12 + head) * 1568 + nn) * 64 + c;
                if (which == 0)      qb[idx] = f2bf(val);
                else if (which == 1) kb2[(((size_t)(b_ * 12 + head)) * 1600 + nn) * 64 + c] = f2bf(val * 0.18033688f);
                else                 vb[idx] = f2bf(val);
            }
        }
    }
}

// v [48][1568][64] -> vtb [48][64][1600]
__global__ __launch_bounds__(256) void k_vt(const unsigned short* __restrict__ vb,
                                            unsigned short* __restrict__ vtb) {
    __shared__ unsigned short t[64][72];
    int bh = blockIdx.y;
    int n0 = blockIdx.x * 64;
    int tid = threadIdx.x;
    int r = tid >> 2, cg = (tid & 3) * 16;
    int n = n0 + r;
    if (n > 1567) n = 1567;
    const unsigned short* src = vb + ((size_t)bh * 1568 + n) * 64 + cg;
    *reinterpret_cast<uint4*>(&t[r][cg]) = *reinterpret_cast<const uint4*>(src);
    *reinterpret_cast<uint4*>(&t[r][cg + 8]) = *reinterpret_cast<const uint4*>(src + 8);
    __syncthreads();
    int c = tid >> 2, ng = (tid & 3) * 16;
    if (n0 + ng < 1568) {
        unsigned short buf[16];
#pragma unroll
        for (int i = 0; i < 16; ++i) buf[i] = t[ng + i][c];
        unsigned short* dst = vtb + ((size_t)bh * 64 + c) * 1600 + n0 + ng;
        *reinterpret_cast<uint4*>(dst) = *reinterpret_cast<uint4*>(&buf[0]);
        *reinterpret_cast<uint4*>(dst + 8) = *reinterpret_cast<uint4*>(&buf[8]);
    }
}

// ---------------- attention: double-buffered K/I/V staging (round-7 pipeline), slim ind ----------------
// grid (48 bh, 13 qt); block 256 = 4 waves x 32 q-rows. Softmax in exp2 domain.
// ind staged as 40 cols (80 B/row, packed lane-linear): qbias dims >=37 are 0, so reads of
// cols 40..63 hit adjacent finite staged data x 0 = exact 0 (identical math to full staging).
// LDS: buf = [K 8192 | I 5120 | V 8192] = 21504; x2 = 43008; pP 4x2304 @43008; total 52224
// -> 3 blocks/CU (52224*3 <= 163840): all 624 blocks co-resident, no straggler round.
__global__ __launch_bounds__(256, 3) void k_attn(const unsigned short* __restrict__ qb,
                                                 const unsigned short* __restrict__ kb2,
                                                 const unsigned short* __restrict__ indb,
                                                 const unsigned short* __restrict__ vtb,
                                                 const unsigned short* __restrict__ Tbf,
                                                 unsigned short* __restrict__ obf) {
    __shared__ __align__(16) char smem[52224];
    const int lane = threadIdx.x & 63;
    const int wid = threadIdx.x >> 6;
    const int quad = lane >> 4;
    const int l16 = lane & 15;
    const int sr = lane >> 3;
    const int sc = lane & 7;
    const int bh = blockIdx.x;
    const int qt = blockIdx.y;

    unsigned short* pw = (unsigned short*)(smem + 43008 + wid * 2304);  // per-wave P [16][72]
    unsigned short* tR = (unsigned short*)(smem + wid * 5120);          // transient qR [32][80] (buf0)
    unsigned short* tB = (unsigned short*)(smem + 21504 + wid * 4608);  // transient qbx [32][72] (buf1)

    // ind staging source offsets (packed 80-B rows, 5 full-wave DMAs over 320 chunks):
    // chunk-linear i -> row i/5, col-chunk i%5. Wave w issues i = w*64+lane; wave 0 also i = 256+lane.
    const int iA = wid * 64 + lane;
    const int ioA = (iA / 5) * 128 + (iA % 5) * 16;
    const int iB = 256 + lane;
    const int ioB = (iB / 5) * 128 + (iB % 5) * 16;

    // ---- prologue: Q frags, qR = q.T^T (log2e-scaled), extended-Q bias frags ----
    bf16x8 a_q0[2], a_q1[2], a_b0[2], a_b1[2];
#pragma unroll
    for (int mt = 0; mt < 2; ++mt) {
        int qrow = qt * 128 + wid * 32 + mt * 16 + l16;
        if (qrow > 1567) qrow = 1567;
        const unsigned short* qp = qb + ((size_t)bh * 1568 + qrow) * 64 + quad * 8;
        a_q0[mt] = ld_bf8(qp);
        a_q1[mt] = ld_bf8(qp + 32);
    }
#pragma unroll
    for (int mt = 0; mt < 2; ++mt) {
#pragma unroll
        for (int ng = 0; ng < 5; ++ng) {
            const unsigned short* tp = Tbf + (size_t)(ng * 16 + l16) * 64 + quad * 8;
            f32x4 t = {};
            t = MFMA16(a_q0[mt], ld_bf8(tp), t);
            t = MFMA16(a_q1[mt], ld_bf8(tp + 32), t);
#pragma unroll
            for (int r = 0; r < 4; ++r)
                tR[(mt * 16 + quad * 4 + r) * 80 + ng * 16 + l16] = f2bf(t[r]);
        }
    }
#pragma unroll
    for (int mt = 0; mt < 2; ++mt) {
        int gq = qt * 128 + wid * 32 + mt * 16 + l16;
        if (gq > 1567) gq = 1567;
        int qd = gq / 196;
        int rm = gq - qd * 196;
        int qh = rm / 14;
        int qw = rm - qh * 14;
        const unsigned short* qr = tR + (mt * 16 + l16) * 80;
        unsigned short* qxr = tB + (mt * 16 + l16) * 72;
#pragma unroll
        for (int t = 0; t < 16; ++t) {
            int dd = quad * 16 + t;
            unsigned short v = 0;
            if (dd < 8)        v = qr[qd - dd + 7];
            else if (dd < 22)  v = qr[15 + qh - (dd - 8) + 13];
            else if (dd < 36)  v = qr[42 + qw - (dd - 22) + 13];
            else if (dd == 36) v = 0xC6EA;  // bf16(-30000): exp2 -> 0 pad-key mask
            qxr[dd] = v;
        }
    }
#pragma unroll
    for (int mt = 0; mt < 2; ++mt) {
        const unsigned short* qx = tB + (mt * 16 + l16) * 72;
        a_b0[mt] = ld_bf8(qx + quad * 8);
        a_b1[mt] = ld_bf8(qx + 32 + quad * 8);
    }
    // CROSS-WAVE hazard: stage() below overwrites other waves' tR/tB regions.
    __syncthreads();

    const char* kbh_b = (const char*)(kb2 + (size_t)bh * 1600 * 64);
    const char* ind_b = (const char*)indb;
    const char* vbh_b = (const char*)(vtb + (size_t)bh * 64 * 1600);

    // DMA stage a 64-key tile: K (swizzled) | ind (packed 40-col) | V (swizzled)
    auto stage = [&](char* sbase, int kb0) {
#pragma unroll
        for (int j = 0; j < 2; ++j) {
            int loc = wid * 16 + j * 8 + sr;
            int gc = ((sc + loc) & 7) * 16;
            dma16(kbh_b + (size_t)(kb0 + loc) * 128 + gc, sbase + (wid * 16 + j * 8) * 128);
            dma16(vbh_b + (size_t)loc * 3200 + (size_t)kb0 * 2 + gc,
                  sbase + 13312 + (wid * 16 + j * 8) * 128);
        }
        dma16(ind_b + (size_t)kb0 * 128 + ioA, sbase + 8192 + wid * 1024);
        if (wid == 0)
            dma16(ind_b + (size_t)kb0 * 128 + ioB, sbase + 8192 + 4096);
    };

    float l_p[2][4] = {};   // per-lane partial rowsums (reduced once at the end)
    f32x4 Oacc[2][4] = {};

    stage(smem, 0);
    __syncthreads();

    for (int kt = 0; kt < 25; ++kt) {
        char* cur = smem + (kt & 1) * 21504;
        if (kt < 24) stage(smem + ((kt + 1) & 1) * 21504, (kt + 1) * 64);  // prefetch next tile

        const unsigned short* sK = (const unsigned short*)cur;
        const unsigned short* sI = (const unsigned short*)(cur + 8192);
        const unsigned short* sV = (const unsigned short*)(cur + 13312);

        // ---- S = [q|qbias].[k*0.125*log2e|ind], exp2, partial rowsum ----
        float p[2][4][4];
#pragma unroll
        for (int kg = 0; kg < 4; ++kg) {
            int key = kg * 16 + l16;
            const unsigned short* kr = sK + key * 64;
            bf16x8 bk0 = ld_bf8(kr + ((quad - key) & 7) * 8);
            bf16x8 bk1 = ld_bf8(kr + ((quad + 4 - key) & 7) * 8);
            const unsigned short* ir = sI + key * 40;   // packed 80-B rows, no swizzle
            bf16x8 bi0 = ld_bf8(ir + quad * 8);
            bf16x8 bi1 = ld_bf8(ir + 32 + quad * 8);    // quads 1..3 read past row: x 0 = exact 0
#pragma unroll
            for (int mt = 0; mt < 2; ++mt) {
                f32x4 t = {};
                t = MFMA16(a_q0[mt], bk0, t);
                t = MFMA16(a_q1[mt], bk1, t);
                t = MFMA16(a_b0[mt], bi0, t);
                t = MFMA16(a_b1[mt], bi1, t);
#pragma unroll
                for (int r = 0; r < 4; ++r) {
                    union { float f; unsigned int u; } c;
                    c.f = EXP2(t[r]);
                    c.u &= 0xFFFF0000u;       // truncate to bf16-representable (consistent num/denom)
                    p[mt][kg][r] = c.f;
                    l_p[mt][r] += c.f;
                }
            }
        }
        // ---- V frags into registers (shared across both m-tiles) ----
        bf16x8 v0[4], v1[4];
#pragma unroll
        for (int cg = 0; cg < 4; ++cg) {
            int dim = cg * 16 + l16;
            const unsigned short* vr = sV + dim * 64;
            v0[cg] = ld_bf8(vr + ((quad - dim) & 7) * 8);
            v1[cg] = ld_bf8(vr + ((quad + 4 - dim) & 7) * 8);
        }
        // ---- per-mt: P C->A transform via wave-private LDS, then PV ----
#pragma unroll
        for (int mt = 0; mt < 2; ++mt) {
#pragma unroll
            for (int kg = 0; kg < 4; ++kg)
#pragma unroll
                for (int r = 0; r < 4; ++r) {
                    union { float f; unsigned int u; } c;
                    c.f = p[mt][kg][r];
                    pw[(quad * 4 + r) * 72 + kg * 16 + l16] = (unsigned short)(c.u >> 16);
                }
            const unsigned short* pr = pw + l16 * 72;
            bf16x8 ap0 = ld_bf8(pr + quad * 8);
            bf16x8 ap1 = ld_bf8(pr + 32 + quad * 8);
#pragma unroll
            for (int cg = 0; cg < 4; ++cg) {
                Oacc[mt][cg] = MFMA16(ap0, v0[cg], Oacc[mt][cg]);
                Oacc[mt][cg] = MFMA16(ap1, v1[cg], Oacc[mt][cg]);
            }
        }
        __syncthreads();  // cur consumed; prefetch drained; buffers swap
    }

    // ---- final rowsum reduce + epilogue ----
    int b_ = bh / 12;
    int head = bh - b_ * 12;
    unsigned short* ob = obf + (size_t)b_ * 1568 * 768 + head * 64;
#pragma unroll
    for (int mt = 0; mt < 2; ++mt)
#pragma unroll
        for (int r = 0; r < 4; ++r) {
            float v = l_p[mt][r];
            v += __shfl_xor(v, 1);
            v += __shfl_xor(v, 2);
            v += __shfl_xor(v, 4);
            v += __shfl_xor(v, 8);
            int gq = qt * 128 + wid * 32 + mt * 16 + quad * 4 + r;
            if (gq < 1568) {
                float inv = 1.0f / v;
#pragma unroll
                for (int cg = 0; cg < 4; ++cg)
                    ob[(size_t)gq * 768 + cg * 16 + l16] = f2bf(Oacc[mt][cg][r] * inv);
            }
        }
}

// ---------------- GEMM3: out = O @ proj_w + proj_b (fp32 out), LDS-staged ----------------
__global__ __launch_bounds__(256, 3) void k_proj(const unsigned short* __restrict__ obf,
                                                 const unsigned short* __restrict__ w2t,
                                                 const float* __restrict__ proj_b,
                                                 float* __restrict__ out) {
    __shared__ __align__(16) char smem[32768];
    f32x4 acc[4][4] = {};
    gemm_core(obf, w2t, blockIdx.x * 128, blockIdx.y * 128, smem, acc);

    const int lane = threadIdx.x & 63;
    const int wid = threadIdx.x >> 6;
    const int ww = wid & 1, wh = wid >> 1;
    const int quad = lane >> 4, l16 = lane & 15;
#pragma unroll
    for (int j = 0; j < 4; ++j) {
        int n = blockIdx.y * 128 + ww * 64 + j * 16 + l16;
        float bias = proj_b[n];
#pragma unroll
        for (int i = 0; i < 4; ++i) {
#pragma unroll
            for (int r = 0; r < 4; ++r) {
                int m = blockIdx.x * 128 + wh * 64 + i * 16 + quad * 4 + r;
                out[(size_t)m * 768 + n] = acc[i][j][r] + bias;
            }
        }
    }
}

// ---------------- launch ----------------
extern "C" void kernel_launch(void* const* d_in, const int* in_sizes, int n_in,
                              void* d_out, int out_size, void* d_ws, size_t ws_size,
                              hipStream_t stream) {
    const float* x      = (const float*)d_in[0];
    const float* qkv_w  = (const float*)d_in[1];
    const float* qkv_b  = (const float*)d_in[2];
    const float* proj_w = (const float*)d_in[3];
    const float* proj_b = (const float*)d_in[4];
    const float* rd     = (const float*)d_in[5];
    const float* rh     = (const float*)d_in[6];
    const float* rw     = (const float*)d_in[7];
    float* out = (float*)d_out;

    char* ws = (char*)d_ws;
    size_t off = 0;
    auto alloc = [&](size_t bytes) {
        char* p = ws + off;
        off += (bytes + 255) & ~(size_t)255;
        return p;
    };
    unsigned short* xbf  = (unsigned short*)alloc((size_t)6272 * 768 * 2);   // reused as obf
    unsigned short* w1t  = (unsigned short*)alloc((size_t)2304 * 768 * 2);
    unsigned short* w2t  = (unsigned short*)alloc((size_t)768 * 768 * 2);
    unsigned short* Tbf  = (unsigned short*)alloc((size_t)80 * 64 * 2);
    unsigned short* qb   = (unsigned short*)alloc((size_t)48 * 1568 * 64 * 2);
    unsigned short* kb2  = (unsigned short*)alloc((size_t)48 * 1600 * 64 * 2);
    unsigned short* vtb  = (unsigned short*)alloc((size_t)48 * 64 * 1600 * 2);
    unsigned short* indb = (unsigned short*)alloc((size_t)1600 * 64 * 2);
    unsigned short* obf  = xbf;                 // x dead after k_qkv
    unsigned short* vb   = (unsigned short*)d_out;  // d_out as scratch: k_proj overwrites it last

    hipLaunchKernelGGL(k_cvt_x, dim3(4704), dim3(256), 0, stream, x, xbf, 1204224);
    hipLaunchKernelGGL(k_transpose, dim3(12, 36), dim3(256), 0, stream, qkv_w, w1t, 768, 2304);
    hipLaunchKernelGGL(k_transpose, dim3(12, 12), dim3(256), 0, stream, proj_w, w2t, 768, 768);
    hipLaunchKernelGGL(k_tables, dim3(20), dim3(256), 0, stream, rd, rh, rw, Tbf);
    hipLaunchKernelGGL(k_fill_ind, dim3(400), dim3(256), 0, stream, indb);
    hipLaunchKernelGGL(k_qkv, dim3(49, 18), dim3(256), 0, stream, xbf, w1t, qkv_b, qb, kb2, vb);
    hipLaunchKernelGGL(k_vt, dim3(25, 48), dim3(256), 0, stream, vb, vtb);
    hipLaunchKernelGGL(k_attn, dim3(48, 13), dim3(256), 0, stream, qb, kb2, indb, vtb, Tbf, obf);
    hipLaunchKernelGGL(k_proj, dim3(49, 6), dim3(256), 0, stream, obf, w2t, proj_b, out);
}

// Round 11
// 226.626 us; speedup vs baseline: 1.2482x; 1.0472x over previous
//
#include <hip/hip_runtime.h>

// Shapes (fixed): B=4, D=8, H=14, W=14, C=768, NH=12, hd=64, N=1568 (pad 1600), BH=48, M=6272

typedef __bf16 bf16x8 __attribute__((ext_vector_type(8)));
typedef float f32x4 __attribute__((ext_vector_type(4)));

#define MFMA16(a, b, c) __builtin_amdgcn_mfma_f32_16x16x32_bf16((a), (b), (c), 0, 0, 0)

#if __has_builtin(__builtin_amdgcn_exp2f)
#define EXP2(x) __builtin_amdgcn_exp2f(x)
#else
#define EXP2(x) exp2f(x)
#endif

static __device__ __forceinline__ unsigned short f2bf(float f) {
    union { float f; unsigned int u; } v; v.f = f;
    unsigned int u = v.u;
    return (unsigned short)((u + 0x7fffu + ((u >> 16) & 1u)) >> 16);
}

static __device__ __forceinline__ bf16x8 ld_bf8(const unsigned short* p) {
    return *reinterpret_cast<const bf16x8*>(p);
}

// async global->LDS DMA, 16 B per lane; lds dest = wave-uniform base + lane*16
static __device__ __forceinline__ void dma16(const void* g, void* l) {
    __builtin_amdgcn_global_load_lds(
        (const __attribute__((address_space(1))) void*)g,
        (__attribute__((address_space(3))) void*)l, 16, 0, 0);
}

// ---------------- merged prep kernel ----------------
// sections: [0,4704) cvt_x | [4704,5136) transpose qkv_w | [5136,5280) transpose proj_w
//           | [5280,5300) tables | [5300,5700) fill_ind

static __device__ __forceinline__ void do_transpose(const float* __restrict__ w,
                                                    unsigned short* __restrict__ wt,
                                                    int K, int N, int bx, int by,
                                                    float (*tile)[65]) {
    int kt = bx * 64;
    int nt = by * 64;
    int tid = threadIdx.x;
    int r = tid >> 2;
    int cg = tid & 3;
#pragma unroll
    for (int i = 0; i < 4; ++i) {
        int c = cg * 16 + i * 4;
        float4 v = *reinterpret_cast<const float4*>(&w[(size_t)(kt + r) * N + nt + c]);
        tile[r][c + 0] = v.x; tile[r][c + 1] = v.y; tile[r][c + 2] = v.z; tile[r][c + 3] = v.w;
    }
    __syncthreads();
#pragma unroll
    for (int i = 0; i < 4; ++i) {
        int c = cg * 16 + i * 4;
        ushort4 o;
        o.x = f2bf(tile[c + 0][r]);
        o.y = f2bf(tile[c + 1][r]);
        o.z = f2bf(tile[c + 2][r]);
        o.w = f2bf(tile[c + 3][r]);
        *reinterpret_cast<ushort4*>(&wt[(size_t)(nt + r) * K + kt + c]) = o;
    }
}

__global__ __launch_bounds__(256) void k_prep(const float* __restrict__ x,
                                              unsigned short* __restrict__ xbf,
                                              const float* __restrict__ qkv_w,
                                              unsigned short* __restrict__ w1t,
                                              const float* __restrict__ proj_w,
                                              unsigned short* __restrict__ w2t,
                                              const float* __restrict__ rd,
                                              const float* __restrict__ rh,
                                              const float* __restrict__ rw,
                                              unsigned short* __restrict__ Tbf,
                                              unsigned short* __restrict__ indb) {
    __shared__ float tile[64][65];
    int bid = blockIdx.x;
    if (bid < 4704) {
        int i = bid * 256 + threadIdx.x;
        if (i < 1204224) {
            float4 v = reinterpret_cast<const float4*>(x)[i];
            ushort4 o;
            o.x = f2bf(v.x); o.y = f2bf(v.y); o.z = f2bf(v.z); o.w = f2bf(v.w);
            reinterpret_cast<ushort4*>(xbf)[i] = o;
        }
    } else if (bid < 5136) {
        int t = bid - 4704;                     // 432 = 12 x 36
        do_transpose(qkv_w, w1t, 768, 2304, t % 12, t / 12, tile);
    } else if (bid < 5280) {
        int t = bid - 5136;                     // 144 = 12 x 12
        do_transpose(proj_w, w2t, 768, 768, t % 12, t / 12, tile);
    } else if (bid < 5300) {
        // rel-pos tables, PRE-SCALED by log2(e) (softmax runs in exp2 domain)
        int i = (bid - 5280) * 256 + threadIdx.x;
        if (i < 80 * 64) {
            int row = i >> 6, c = i & 63;
            float v = 0.f;
            if (row < 15) v = rd[row * 64 + c];
            else if (row < 42) v = rh[(row - 15) * 64 + c];
            else if (row < 69) v = rw[(row - 42) * 64 + c];
            Tbf[i] = f2bf(v * 1.44269504f);
        }
    } else {
        // indicator table ind[1600][64]: one-hot kd@0..7, kh@8..21, kw@22..35; pad keys 1.0@36
        int i = (bid - 5300) * 256 + threadIdx.x;
        if (i < 1600 * 64) {
            int key = i >> 6, c = i & 63;
            unsigned short v = 0;
            if (key < 1568) {
                int kd = key / 196;
                int r = key - kd * 196;
                int kh = r / 14;
                int kw = r - kh * 14;
                if (c == kd || c == 8 + kh || c == 22 + kw) v = 0x3F80;  // bf16 1.0
            } else {
                if (c == 36) v = 0x3F80;
            }
            indb[i] = v;
        }
    }
}

// ---------------- shared GEMM core: LDS-staged 128x128 tile, BK=64, K=768 ----------------
static __device__ __forceinline__ void gemm_core(const unsigned short* __restrict__ A,
                                                 const unsigned short* __restrict__ B,
                                                 int M_base, int N_base,
                                                 char* smem, f32x4 acc[4][4]) {
    const int lane = threadIdx.x & 63;
    const int wid = threadIdx.x >> 6;
    const int ww = wid & 1, wh = wid >> 1;
    const int quad = lane >> 4, l16 = lane & 15;
    const int sr = lane >> 3, sc = lane & 7;
    unsigned short* sA = (unsigned short*)smem;
    unsigned short* sB = (unsigned short*)(smem + 16384);

    for (int kt = 0; kt < 12; ++kt) {
#pragma unroll
        for (int j = 0; j < 4; ++j) {
            int loc = wid * 32 + j * 8 + sr;
            int gc = ((sc + loc) & 7) * 16;
            dma16((const char*)A + (size_t)(M_base + loc) * 1536 + kt * 128 + gc,
                  (char*)sA + (wid * 32 + j * 8) * 128);
            dma16((const char*)B + (size_t)(N_base + loc) * 1536 + kt * 128 + gc,
                  (char*)sB + (wid * 32 + j * 8) * 128);
        }
        __syncthreads();
#pragma unroll
        for (int s = 0; s < 2; ++s) {
            bf16x8 af[4], bfr[4];
#pragma unroll
            for (int i = 0; i < 4; ++i) {
                int ar = wh * 64 + i * 16 + l16;
                af[i] = ld_bf8(sA + ar * 64 + (((s * 4 + quad) - ar) & 7) * 8);
                int br = ww * 64 + i * 16 + l16;
                bfr[i] = ld_bf8(sB + br * 64 + (((s * 4 + quad) - br) & 7) * 8);
            }
#pragma unroll
            for (int i = 0; i < 4; ++i)
#pragma unroll
                for (int j2 = 0; j2 < 4; ++j2)
                    acc[i][j2] = MFMA16(af[i], bfr[j2], acc[i][j2]);
        }
        __syncthreads();
    }
}

// ---------------- 64x128 GEMM core (for the skinny proj GEMM): A 64 rows, B 128 rows ----------------
// wave w computes n-strip w*32..w*32+31 over all 64 m. LDS: sA 8192 @0, sB 16384 @8192 = 24576.
static __device__ __forceinline__ void gemm_core64(const unsigned short* __restrict__ A,
                                                   const unsigned short* __restrict__ B,
                                                   int M_base, int N_base,
                                                   char* smem, f32x4 acc[4][2]) {
    const int lane = threadIdx.x & 63;
    const int wid = threadIdx.x >> 6;
    const int quad = lane >> 4, l16 = lane & 15;
    const int sr = lane >> 3, sc = lane & 7;
    unsigned short* sA = (unsigned short*)smem;
    unsigned short* sB = (unsigned short*)(smem + 8192);

    for (int kt = 0; kt < 12; ++kt) {
#pragma unroll
        for (int j = 0; j < 2; ++j) {
            int loc = wid * 16 + j * 8 + sr;
            int gc = ((sc + loc) & 7) * 16;
            dma16((const char*)A + (size_t)(M_base + loc) * 1536 + kt * 128 + gc,
                  (char*)sA + (wid * 16 + j * 8) * 128);
        }
#pragma unroll
        for (int j = 0; j < 4; ++j) {
            int loc = wid * 32 + j * 8 + sr;
            int gc = ((sc + loc) & 7) * 16;
            dma16((const char*)B + (size_t)(N_base + loc) * 1536 + kt * 128 + gc,
                  (char*)sB + (wid * 32 + j * 8) * 128);
        }
        __syncthreads();
#pragma unroll
        for (int s = 0; s < 2; ++s) {
            bf16x8 af[4], bfr[2];
#pragma unroll
            for (int i = 0; i < 4; ++i) {
                int ar = i * 16 + l16;
                af[i] = ld_bf8(sA + ar * 64 + (((s * 4 + quad) - ar) & 7) * 8);
            }
#pragma unroll
            for (int j = 0; j < 2; ++j) {
                int br = wid * 32 + j * 16 + l16;
                bfr[j] = ld_bf8(sB + br * 64 + (((s * 4 + quad) - br) & 7) * 8);
            }
#pragma unroll
            for (int i = 0; i < 4; ++i)
#pragma unroll
                for (int j = 0; j < 2; ++j)
                    acc[i][j] = MFMA16(af[i], bfr[j], acc[i][j]);
        }
        __syncthreads();
    }
}

// ---------------- GEMM1: qkv = x @ qkv_w + b -> q, k(scaled 0.125*log2e), v(natural) ----------------
__global__ __launch_bounds__(256, 4) void k_qkv(const unsigned short* __restrict__ xbf,
                                                const unsigned short* __restrict__ w1t,
                                                const float* __restrict__ qkv_b,
                                                unsigned short* __restrict__ qb,
                                                unsigned short* __restrict__ kb2,
                                                unsigned short* __restrict__ vb) {
    __shared__ __align__(16) char smem[32768];
    f32x4 acc[4][4] = {};
    gemm_core(xbf, w1t, blockIdx.x * 128, blockIdx.y * 128, smem, acc);

    const int lane = threadIdx.x & 63;
    const int wid = threadIdx.x >> 6;
    const int ww = wid & 1, wh = wid >> 1;
    const int quad = lane >> 4, l16 = lane & 15;
#pragma unroll
    for (int j = 0; j < 4; ++j) {
        int n = blockIdx.y * 128 + ww * 64 + j * 16 + l16;
        float bias = qkv_b[n];
        int which = n / 768;
        int rem = n - which * 768;
        int head = rem >> 6;
        int c = rem & 63;
#pragma unroll
        for (int i = 0; i < 4; ++i) {
#pragma unroll
            for (int r = 0; r < 4; ++r) {
                int m = blockIdx.x * 128 + wh * 64 + i * 16 + quad * 4 + r;
                float val = acc[i][j][r] + bias;
                int b_ = m / 1568;
                int nn = m - b_ * 1568;
                size_t idx = ((size_t)(b_ * 12 + head) * 1568 + nn) * 64 + c;
                if (which == 0)      qb[idx] = f2bf(val);
                else if (which == 1) kb2[(((size_t)(b_ * 12 + head)) * 1600 + nn) * 64 + c] = f2bf(val * 0.18033688f);
                else                 vb[idx] = f2bf(val);
            }
        }
    }
}

// v [48][1568][64] -> vtb [48][64][1600]
__global__ __launch_bounds__(256) void k_vt(const unsigned short* __restrict__ vb,
                                            unsigned short* __restrict__ vtb) {
    __shared__ unsigned short t[64][72];
    int bh = blockIdx.y;
    int n0 = blockIdx.x * 64;
    int tid = threadIdx.x;
    int r = tid >> 2, cg = (tid & 3) * 16;
    int n = n0 + r;
    if (n > 1567) n = 1567;
    const unsigned short* src = vb + ((size_t)bh * 1568 + n) * 64 + cg;
    *reinterpret_cast<uint4*>(&t[r][cg]) = *reinterpret_cast<const uint4*>(src);
    *reinterpret_cast<uint4*>(&t[r][cg + 8]) = *reinterpret_cast<const uint4*>(src + 8);
    __syncthreads();
    int c = tid >> 2, ng = (tid & 3) * 16;
    if (n0 + ng < 1568) {
        unsigned short buf[16];
#pragma unroll
        for (int i = 0; i < 16; ++i) buf[i] = t[ng + i][c];
        unsigned short* dst = vtb + ((size_t)bh * 64 + c) * 1600 + n0 + ng;
        *reinterpret_cast<uint4*>(dst) = *reinterpret_cast<uint4*>(&buf[0]);
        *reinterpret_cast<uint4*>(dst + 8) = *reinterpret_cast<uint4*>(&buf[8]);
    }
}

// ---------------- attention: double-buffered K/I/V staging, slim ind (round-10, unchanged) ----------------
__global__ __launch_bounds__(256, 3) void k_attn(const unsigned short* __restrict__ qb,
                                                 const unsigned short* __restrict__ kb2,
                                                 const unsigned short* __restrict__ indb,
                                                 const unsigned short* __restrict__ vtb,
                                                 const unsigned short* __restrict__ Tbf,
                                                 unsigned short* __restrict__ obf) {
    __shared__ __align__(16) char smem[52224];
    const int lane = threadIdx.x & 63;
    const int wid = threadIdx.x >> 6;
    const int quad = lane >> 4;
    const int l16 = lane & 15;
    const int sr = lane >> 3;
    const int sc = lane & 7;
    const int bh = blockIdx.x;
    const int qt = blockIdx.y;

    unsigned short* pw = (unsigned short*)(smem + 43008 + wid * 2304);  // per-wave P [16][72]
    unsigned short* tR = (unsigned short*)(smem + wid * 5120);          // transient qR [32][80] (buf0)
    unsigned short* tB = (unsigned short*)(smem + 21504 + wid * 4608);  // transient qbx [32][72] (buf1)

    const int iA = wid * 64 + lane;
    const int ioA = (iA / 5) * 128 + (iA % 5) * 16;
    const int iB = 256 + lane;
    const int ioB = (iB / 5) * 128 + (iB % 5) * 16;

    // ---- prologue: Q frags, qR = q.T^T (log2e-scaled), extended-Q bias frags ----
    bf16x8 a_q0[2], a_q1[2], a_b0[2], a_b1[2];
#pragma unroll
    for (int mt = 0; mt < 2; ++mt) {
        int qrow = qt * 128 + wid * 32 + mt * 16 + l16;
        if (qrow > 1567) qrow = 1567;
        const unsigned short* qp = qb + ((size_t)bh * 1568 + qrow) * 64 + quad * 8;
        a_q0[mt] = ld_bf8(qp);
        a_q1[mt] = ld_bf8(qp + 32);
    }
#pragma unroll
    for (int mt = 0; mt < 2; ++mt) {
#pragma unroll
        for (int ng = 0; ng < 5; ++ng) {
            const unsigned short* tp = Tbf + (size_t)(ng * 16 + l16) * 64 + quad * 8;
            f32x4 t = {};
            t = MFMA16(a_q0[mt], ld_bf8(tp), t);
            t = MFMA16(a_q1[mt], ld_bf8(tp + 32), t);
#pragma unroll
            for (int r = 0; r < 4; ++r)
                tR[(mt * 16 + quad * 4 + r) * 80 + ng * 16 + l16] = f2bf(t[r]);
        }
    }
#pragma unroll
    for (int mt = 0; mt < 2; ++mt) {
        int gq = qt * 128 + wid * 32 + mt * 16 + l16;
        if (gq > 1567) gq = 1567;
        int qd = gq / 196;
        int rm = gq - qd * 196;
        int qh = rm / 14;
        int qw = rm - qh * 14;
        const unsigned short* qr = tR + (mt * 16 + l16) * 80;
        unsigned short* qxr = tB + (mt * 16 + l16) * 72;
#pragma unroll
        for (int t = 0; t < 16; ++t) {
            int dd = quad * 16 + t;
            unsigned short v = 0;
            if (dd < 8)        v = qr[qd - dd + 7];
            else if (dd < 22)  v = qr[15 + qh - (dd - 8) + 13];
            else if (dd < 36)  v = qr[42 + qw - (dd - 22) + 13];
            else if (dd == 36) v = 0xC6EA;  // bf16(-30000): exp2 -> 0 pad-key mask
            qxr[dd] = v;
        }
    }
#pragma unroll
    for (int mt = 0; mt < 2; ++mt) {
        const unsigned short* qx = tB + (mt * 16 + l16) * 72;
        a_b0[mt] = ld_bf8(qx + quad * 8);
        a_b1[mt] = ld_bf8(qx + 32 + quad * 8);
    }
    // CROSS-WAVE hazard: stage() below overwrites other waves' tR/tB regions.
    __syncthreads();

    const char* kbh_b = (const char*)(kb2 + (size_t)bh * 1600 * 64);
    const char* ind_b = (const char*)indb;
    const char* vbh_b = (const char*)(vtb + (size_t)bh * 64 * 1600);

    auto stage = [&](char* sbase, int kb0) {
#pragma unroll
        for (int j = 0; j < 2; ++j) {
            int loc = wid * 16 + j * 8 + sr;
            int gc = ((sc + loc) & 7) * 16;
            dma16(kbh_b + (size_t)(kb0 + loc) * 128 + gc, sbase + (wid * 16 + j * 8) * 128);
            dma16(vbh_b + (size_t)loc * 3200 + (size_t)kb0 * 2 + gc,
                  sbase + 13312 + (wid * 16 + j * 8) * 128);
        }
        dma16(ind_b + (size_t)kb0 * 128 + ioA, sbase + 8192 + wid * 1024);
        if (wid == 0)
            dma16(ind_b + (size_t)kb0 * 128 + ioB, sbase + 8192 + 4096);
    };

    float l_p[2][4] = {};
    f32x4 Oacc[2][4] = {};

    stage(smem, 0);
    __syncthreads();

    for (int kt = 0; kt < 25; ++kt) {
        char* cur = smem + (kt & 1) * 21504;
        if (kt < 24) stage(smem + ((kt + 1) & 1) * 21504, (kt + 1) * 64);

        const unsigned short* sK = (const unsigned short*)cur;
        const unsigned short* sI = (const unsigned short*)(cur + 8192);
        const unsigned short* sV = (const unsigned short*)(cur + 13312);

        float p[2][4][4];
#pragma unroll
        for (int kg = 0; kg < 4; ++kg) {
            int key = kg * 16 + l16;
            const unsigned short* kr = sK + key * 64;
            bf16x8 bk0 = ld_bf8(kr + ((quad - key) & 7) * 8);
            bf16x8 bk1 = ld_bf8(kr + ((quad + 4 - key) & 7) * 8);
            const unsigned short* ir = sI + key * 40;
            bf16x8 bi0 = ld_bf8(ir + quad * 8);
            bf16x8 bi1 = ld_bf8(ir + 32 + quad * 8);
#pragma unroll
            for (int mt = 0; mt < 2; ++mt) {
                f32x4 t = {};
                t = MFMA16(a_q0[mt], bk0, t);
                t = MFMA16(a_q1[mt], bk1, t);
                t = MFMA16(a_b0[mt], bi0, t);
                t = MFMA16(a_b1[mt], bi1, t);
#pragma unroll
                for (int r = 0; r < 4; ++r) {
                    union { float f; unsigned int u; } c;
                    c.f = EXP2(t[r]);
                    c.u &= 0xFFFF0000u;
                    p[mt][kg][r] = c.f;
                    l_p[mt][r] += c.f;
                }
            }
        }
        bf16x8 v0[4], v1[4];
#pragma unroll
        for (int cg = 0; cg < 4; ++cg) {
            int dim = cg * 16 + l16;
            const unsigned short* vr = sV + dim * 64;
            v0[cg] = ld_bf8(vr + ((quad - dim) & 7) * 8);
            v1[cg] = ld_bf8(vr + ((quad + 4 - dim) & 7) * 8);
        }
#pragma unroll
        for (int mt = 0; mt < 2; ++mt) {
#pragma unroll
            for (int kg = 0; kg < 4; ++kg)
#pragma unroll
                for (int r = 0; r < 4; ++r) {
                    union { float f; unsigned int u; } c;
                    c.f = p[mt][kg][r];
                    pw[(quad * 4 + r) * 72 + kg * 16 + l16] = (unsigned short)(c.u >> 16);
                }
            const unsigned short* pr = pw + l16 * 72;
            bf16x8 ap0 = ld_bf8(pr + quad * 8);
            bf16x8 ap1 = ld_bf8(pr + 32 + quad * 8);
#pragma unroll
            for (int cg = 0; cg < 4; ++cg) {
                Oacc[mt][cg] = MFMA16(ap0, v0[cg], Oacc[mt][cg]);
                Oacc[mt][cg] = MFMA16(ap1, v1[cg], Oacc[mt][cg]);
            }
        }
        __syncthreads();
    }

    int b_ = bh / 12;
    int head = bh - b_ * 12;
    unsigned short* ob = obf + (size_t)b_ * 1568 * 768 + head * 64;
#pragma unroll
    for (int mt = 0; mt < 2; ++mt)
#pragma unroll
        for (int r = 0; r < 4; ++r) {
            float v = l_p[mt][r];
            v += __shfl_xor(v, 1);
            v += __shfl_xor(v, 2);
            v += __shfl_xor(v, 4);
            v += __shfl_xor(v, 8);
            int gq = qt * 128 + wid * 32 + mt * 16 + quad * 4 + r;
            if (gq < 1568) {
                float inv = 1.0f / v;
#pragma unroll
                for (int cg = 0; cg < 4; ++cg)
                    ob[(size_t)gq * 768 + cg * 16 + l16] = f2bf(Oacc[mt][cg][r] * inv);
            }
        }
}

// ---------------- GEMM3: out = O @ proj_w + proj_b (fp32 out), 64x128 tiles ----------------
// grid (98, 6): 588 blocks -> balanced multi-block/CU residency (was 294 with a 2x tail).
__global__ __launch_bounds__(256, 4) void k_proj(const unsigned short* __restrict__ obf,
                                                 const unsigned short* __restrict__ w2t,
                                                 const float* __restrict__ proj_b,
                                                 float* __restrict__ out) {
    __shared__ __align__(16) char smem[24576];
    f32x4 acc[4][2] = {};
    gemm_core64(obf, w2t, blockIdx.x * 64, blockIdx.y * 128, smem, acc);

    const int lane = threadIdx.x & 63;
    const int wid = threadIdx.x >> 6;
    const int quad = lane >> 4, l16 = lane & 15;
#pragma unroll
    for (int j = 0; j < 2; ++j) {
        int n = blockIdx.y * 128 + wid * 32 + j * 16 + l16;
        float bias = proj_b[n];
#pragma unroll
        for (int i = 0; i < 4; ++i) {
#pragma unroll
            for (int r = 0; r < 4; ++r) {
                int m = blockIdx.x * 64 + i * 16 + quad * 4 + r;
                out[(size_t)m * 768 + n] = acc[i][j][r] + bias;
            }
        }
    }
}

// ---------------- launch ----------------
extern "C" void kernel_launch(void* const* d_in, const int* in_sizes, int n_in,
                              void* d_out, int out_size, void* d_ws, size_t ws_size,
                              hipStream_t stream) {
    const float* x      = (const float*)d_in[0];
    const float* qkv_w  = (const float*)d_in[1];
    const float* qkv_b  = (const float*)d_in[2];
    const float* proj_w = (const float*)d_in[3];
    const float* proj_b = (const float*)d_in[4];
    const float* rd     = (const float*)d_in[5];
    const float* rh     = (const float*)d_in[6];
    const float* rw     = (const float*)d_in[7];
    float* out = (float*)d_out;

    char* ws = (char*)d_ws;
    size_t off = 0;
    auto alloc = [&](size_t bytes) {
        char* p = ws + off;
        off += (bytes + 255) & ~(size_t)255;
        return p;
    };
    unsigned short* xbf  = (unsigned short*)alloc((size_t)6272 * 768 * 2);   // reused as obf
    unsigned short* w1t  = (unsigned short*)alloc((size_t)2304 * 768 * 2);
    unsigned short* w2t  = (unsigned short*)alloc((size_t)768 * 768 * 2);
    unsigned short* Tbf  = (unsigned short*)alloc((size_t)80 * 64 * 2);
    unsigned short* qb   = (unsigned short*)alloc((size_t)48 * 1568 * 64 * 2);
    unsigned short* kb2  = (unsigned short*)alloc((size_t)48 * 1600 * 64 * 2);
    unsigned short* vtb  = (unsigned short*)alloc((size_t)48 * 64 * 1600 * 2);
    unsigned short* indb = (unsigned short*)alloc((size_t)1600 * 64 * 2);
    unsigned short* obf  = xbf;                 // x dead after k_qkv
    unsigned short* vb   = (unsigned short*)d_out;  // d_out as scratch: k_proj overwrites it last

    hipLaunchKernelGGL(k_prep, dim3(5700), dim3(256), 0, stream,
                       x, xbf, qkv_w, w1t, proj_w, w2t, rd, rh, rw, Tbf, indb);
    hipLaunchKernelGGL(k_qkv, dim3(49, 18), dim3(256), 0, stream, xbf, w1t, qkv_b, qb, kb2, vb);
    hipLaunchKernelGGL(k_vt, dim3(25, 48), dim3(256), 0, stream, vb, vtb);
    hipLaunchKernelGGL(k_attn, dim3(48, 13), dim3(256), 0, stream, qb, kb2, indb, vtb, Tbf, obf);
    hipLaunchKernelGGL(k_proj, dim3(98, 6), dim3(256), 0, stream, obf, w2t, proj_b, out);
}

// Round 12
// 221.059 us; speedup vs baseline: 1.2796x; 1.0252x over previous
//
#include <hip/hip_runtime.h>

// Shapes (fixed): B=4, D=8, H=14, W=14, C=768, NH=12, hd=64, N=1568 (pad 1600), BH=48, M=6272

typedef __bf16 bf16x8 __attribute__((ext_vector_type(8)));
typedef float f32x4 __attribute__((ext_vector_type(4)));

#define MFMA16(a, b, c) __builtin_amdgcn_mfma_f32_16x16x32_bf16((a), (b), (c), 0, 0, 0)

#if __has_builtin(__builtin_amdgcn_exp2f)
#define EXP2(x) __builtin_amdgcn_exp2f(x)
#else
#define EXP2(x) exp2f(x)
#endif

static __device__ __forceinline__ unsigned short f2bf(float f) {
    union { float f; unsigned int u; } v; v.f = f;
    unsigned int u = v.u;
    return (unsigned short)((u + 0x7fffu + ((u >> 16) & 1u)) >> 16);
}

static __device__ __forceinline__ bf16x8 ld_bf8(const unsigned short* p) {
    return *reinterpret_cast<const bf16x8*>(p);
}

// async global->LDS DMA, 16 B per lane; lds dest = wave-uniform base + lane*16
static __device__ __forceinline__ void dma16(const void* g, void* l) {
    __builtin_amdgcn_global_load_lds(
        (const __attribute__((address_space(1))) void*)g,
        (__attribute__((address_space(3))) void*)l, 16, 0, 0);
}

// ---------------- merged prep kernel ----------------
// sections: [0,4704) cvt_x | [4704,5136) transpose qkv_w | [5136,5280) transpose proj_w
//           | [5280,5300) tables | [5300,5700) fill_ind

static __device__ __forceinline__ void do_transpose(const float* __restrict__ w,
                                                    unsigned short* __restrict__ wt,
                                                    int K, int N, int bx, int by,
                                                    float (*tile)[65]) {
    int kt = bx * 64;
    int nt = by * 64;
    int tid = threadIdx.x;
    int r = tid >> 2;
    int cg = tid & 3;
#pragma unroll
    for (int i = 0; i < 4; ++i) {
        int c = cg * 16 + i * 4;
        float4 v = *reinterpret_cast<const float4*>(&w[(size_t)(kt + r) * N + nt + c]);
        tile[r][c + 0] = v.x; tile[r][c + 1] = v.y; tile[r][c + 2] = v.z; tile[r][c + 3] = v.w;
    }
    __syncthreads();
#pragma unroll
    for (int i = 0; i < 4; ++i) {
        int c = cg * 16 + i * 4;
        ushort4 o;
        o.x = f2bf(tile[c + 0][r]);
        o.y = f2bf(tile[c + 1][r]);
        o.z = f2bf(tile[c + 2][r]);
        o.w = f2bf(tile[c + 3][r]);
        *reinterpret_cast<ushort4*>(&wt[(size_t)(nt + r) * K + kt + c]) = o;
    }
}

__global__ __launch_bounds__(256) void k_prep(const float* __restrict__ x,
                                              unsigned short* __restrict__ xbf,
                                              const float* __restrict__ qkv_w,
                                              unsigned short* __restrict__ w1t,
                                              const float* __restrict__ proj_w,
                                              unsigned short* __restrict__ w2t,
                                              const float* __restrict__ rd,
                                              const float* __restrict__ rh,
                                              const float* __restrict__ rw,
                                              unsigned short* __restrict__ Tbf,
                                              unsigned short* __restrict__ indb) {
    __shared__ float tile[64][65];
    int bid = blockIdx.x;
    if (bid < 4704) {
        int i = bid * 256 + threadIdx.x;
        if (i < 1204224) {
            float4 v = reinterpret_cast<const float4*>(x)[i];
            ushort4 o;
            o.x = f2bf(v.x); o.y = f2bf(v.y); o.z = f2bf(v.z); o.w = f2bf(v.w);
            reinterpret_cast<ushort4*>(xbf)[i] = o;
        }
    } else if (bid < 5136) {
        int t = bid - 4704;                     // 432 = 12 x 36
        do_transpose(qkv_w, w1t, 768, 2304, t % 12, t / 12, tile);
    } else if (bid < 5280) {
        int t = bid - 5136;                     // 144 = 12 x 12
        do_transpose(proj_w, w2t, 768, 768, t % 12, t / 12, tile);
    } else if (bid < 5300) {
        // rel-pos tables, PRE-SCALED by log2(e) (softmax runs in exp2 domain)
        int i = (bid - 5280) * 256 + threadIdx.x;
        if (i < 80 * 64) {
            int row = i >> 6, c = i & 63;
            float v = 0.f;
            if (row < 15) v = rd[row * 64 + c];
            else if (row < 42) v = rh[(row - 15) * 64 + c];
            else if (row < 69) v = rw[(row - 42) * 64 + c];
            Tbf[i] = f2bf(v * 1.44269504f);
        }
    } else {
        // indicator table ind[1600][64]: one-hot kd@0..7, kh@8..21, kw@22..35; pad keys 1.0@36
        int i = (bid - 5300) * 256 + threadIdx.x;
        if (i < 1600 * 64) {
            int key = i >> 6, c = i & 63;
            unsigned short v = 0;
            if (key < 1568) {
                int kd = key / 196;
                int r = key - kd * 196;
                int kh = r / 14;
                int kw = r - kh * 14;
                if (c == kd || c == 8 + kh || c == 22 + kw) v = 0x3F80;  // bf16 1.0
            } else {
                if (c == 36) v = 0x3F80;
            }
            indb[i] = v;
        }
    }
}

// ---------------- shared GEMM core: LDS-staged 128x128 tile, BK=64, K=768 ----------------
static __device__ __forceinline__ void gemm_core(const unsigned short* __restrict__ A,
                                                 const unsigned short* __restrict__ B,
                                                 int M_base, int N_base,
                                                 char* smem, f32x4 acc[4][4]) {
    const int lane = threadIdx.x & 63;
    const int wid = threadIdx.x >> 6;
    const int ww = wid & 1, wh = wid >> 1;
    const int quad = lane >> 4, l16 = lane & 15;
    const int sr = lane >> 3, sc = lane & 7;
    unsigned short* sA = (unsigned short*)smem;
    unsigned short* sB = (unsigned short*)(smem + 16384);

    for (int kt = 0; kt < 12; ++kt) {
#pragma unroll
        for (int j = 0; j < 4; ++j) {
            int loc = wid * 32 + j * 8 + sr;
            int gc = ((sc + loc) & 7) * 16;
            dma16((const char*)A + (size_t)(M_base + loc) * 1536 + kt * 128 + gc,
                  (char*)sA + (wid * 32 + j * 8) * 128);
            dma16((const char*)B + (size_t)(N_base + loc) * 1536 + kt * 128 + gc,
                  (char*)sB + (wid * 32 + j * 8) * 128);
        }
        __syncthreads();
#pragma unroll
        for (int s = 0; s < 2; ++s) {
            bf16x8 af[4], bfr[4];
#pragma unroll
            for (int i = 0; i < 4; ++i) {
                int ar = wh * 64 + i * 16 + l16;
                af[i] = ld_bf8(sA + ar * 64 + (((s * 4 + quad) - ar) & 7) * 8);
                int br = ww * 64 + i * 16 + l16;
                bfr[i] = ld_bf8(sB + br * 64 + (((s * 4 + quad) - br) & 7) * 8);
            }
#pragma unroll
            for (int i = 0; i < 4; ++i)
#pragma unroll
                for (int j2 = 0; j2 < 4; ++j2)
                    acc[i][j2] = MFMA16(af[i], bfr[j2], acc[i][j2]);
        }
        __syncthreads();
    }
}

// ---------------- 64x128 GEMM core (for the skinny proj GEMM): A 64 rows, B 128 rows ----------------
static __device__ __forceinline__ void gemm_core64(const unsigned short* __restrict__ A,
                                                   const unsigned short* __restrict__ B,
                                                   int M_base, int N_base,
                                                   char* smem, f32x4 acc[4][2]) {
    const int lane = threadIdx.x & 63;
    const int wid = threadIdx.x >> 6;
    const int quad = lane >> 4, l16 = lane & 15;
    const int sr = lane >> 3, sc = lane & 7;
    unsigned short* sA = (unsigned short*)smem;
    unsigned short* sB = (unsigned short*)(smem + 8192);

    for (int kt = 0; kt < 12; ++kt) {
#pragma unroll
        for (int j = 0; j < 2; ++j) {
            int loc = wid * 16 + j * 8 + sr;
            int gc = ((sc + loc) & 7) * 16;
            dma16((const char*)A + (size_t)(M_base + loc) * 1536 + kt * 128 + gc,
                  (char*)sA + (wid * 16 + j * 8) * 128);
        }
#pragma unroll
        for (int j = 0; j < 4; ++j) {
            int loc = wid * 32 + j * 8 + sr;
            int gc = ((sc + loc) & 7) * 16;
            dma16((const char*)B + (size_t)(N_base + loc) * 1536 + kt * 128 + gc,
                  (char*)sB + (wid * 32 + j * 8) * 128);
        }
        __syncthreads();
#pragma unroll
        for (int s = 0; s < 2; ++s) {
            bf16x8 af[4], bfr[2];
#pragma unroll
            for (int i = 0; i < 4; ++i) {
                int ar = i * 16 + l16;
                af[i] = ld_bf8(sA + ar * 64 + (((s * 4 + quad) - ar) & 7) * 8);
            }
#pragma unroll
            for (int j = 0; j < 2; ++j) {
                int br = wid * 32 + j * 16 + l16;
                bfr[j] = ld_bf8(sB + br * 64 + (((s * 4 + quad) - br) & 7) * 8);
            }
#pragma unroll
            for (int i = 0; i < 4; ++i)
#pragma unroll
                for (int j = 0; j < 2; ++j)
                    acc[i][j] = MFMA16(af[i], bfr[j], acc[i][j]);
        }
        __syncthreads();
    }
}

// ---------------- GEMM1: qkv = x @ qkv_w + b -> q, k(scaled 0.125*log2e), V^T(direct) ----------------
// which = blockIdx.y/6 (block-uniform). which==2 blocks route the tile through a padded LDS
// transpose and write vtb[bh][c][nn] coalesced (k_vt kernel eliminated).
__global__ __launch_bounds__(256, 4) void k_qkv(const unsigned short* __restrict__ xbf,
                                                const unsigned short* __restrict__ w1t,
                                                const float* __restrict__ qkv_b,
                                                unsigned short* __restrict__ qb,
                                                unsigned short* __restrict__ kb2,
                                                unsigned short* __restrict__ vtb) {
    __shared__ __align__(16) char smem[36864];   // gemm_core uses [0,32768); transpose uses 128x132 bf16
    f32x4 acc[4][4] = {};
    gemm_core(xbf, w1t, blockIdx.x * 128, blockIdx.y * 128, smem, acc);

    const int lane = threadIdx.x & 63;
    const int wid = threadIdx.x >> 6;
    const int ww = wid & 1, wh = wid >> 1;
    const int quad = lane >> 4, l16 = lane & 15;
    const int which = blockIdx.y / 6;            // 768 = 6*128 -> block-uniform

    if (which < 2) {
#pragma unroll
        for (int j = 0; j < 4; ++j) {
            int n = blockIdx.y * 128 + ww * 64 + j * 16 + l16;
            float bias = qkv_b[n];
            int rem = n - which * 768;
            int head = rem >> 6;
            int c = rem & 63;
#pragma unroll
            for (int i = 0; i < 4; ++i) {
#pragma unroll
                for (int r = 0; r < 4; ++r) {
                    int m = blockIdx.x * 128 + wh * 64 + i * 16 + quad * 4 + r;
                    float val = acc[i][j][r] + bias;
                    int b_ = m / 1568;
                    int nn = m - b_ * 1568;
                    if (which == 0)
                        qb[((size_t)(b_ * 12 + head) * 1568 + nn) * 64 + c] = f2bf(val);
                    else
                        kb2[((size_t)(b_ * 12 + head) * 1600 + nn) * 64 + c] = f2bf(val * 0.18033688f);
                }
            }
        }
    } else {
        // V path: dump tile to LDS (pad 132: store 2-way banks), then write V^T coalesced
        unsigned short (*tile)[132] = (unsigned short (*)[132])smem;
        __syncthreads();   // gemm_core's trailing barrier already passed; re-sync before reuse is safe
#pragma unroll
        for (int j = 0; j < 4; ++j) {
            int n = blockIdx.y * 128 + ww * 64 + j * 16 + l16;
            float bias = qkv_b[n];
#pragma unroll
            for (int i = 0; i < 4; ++i)
#pragma unroll
                for (int r = 0; r < 4; ++r)
                    tile[wh * 64 + i * 16 + quad * 4 + r][ww * 64 + j * 16 + l16] =
                        f2bf(acc[i][j][r] + bias);
        }
        __syncthreads();
        int nl = threadIdx.x >> 1;               // 0..127 (local dim col)
        int mh = (threadIdx.x & 1) * 64;         // m half
        int rem = blockIdx.y * 128 - 1536 + nl;  // dim index in [0,768)
        int head = rem >> 6, c = rem & 63;
#pragma unroll
        for (int k8 = 0; k8 < 64; k8 += 8) {
            int m8 = blockIdx.x * 128 + mh + k8;
            int b_ = m8 / 1568;                  // 1568 % 8 == 0: no straddle inside an 8-chunk
            int nn = m8 - b_ * 1568;
            unsigned short buf[8];
#pragma unroll
            for (int t = 0; t < 8; ++t) buf[t] = tile[mh + k8 + t][nl];
            *reinterpret_cast<uint4*>(vtb + ((size_t)(b_ * 12 + head) * 64 + c) * 1600 + nn) =
                *reinterpret_cast<uint4*>(buf);
        }
    }
}

// ---------------- attention: double-buffered K/I/V staging, slim ind (round-10, unchanged) ----------------
__global__ __launch_bounds__(256, 3) void k_attn(const unsigned short* __restrict__ qb,
                                                 const unsigned short* __restrict__ kb2,
                                                 const unsigned short* __restrict__ indb,
                                                 const unsigned short* __restrict__ vtb,
                                                 const unsigned short* __restrict__ Tbf,
                                                 unsigned short* __restrict__ obf) {
    __shared__ __align__(16) char smem[52224];
    const int lane = threadIdx.x & 63;
    const int wid = threadIdx.x >> 6;
    const int quad = lane >> 4;
    const int l16 = lane & 15;
    const int sr = lane >> 3;
    const int sc = lane & 7;
    const int bh = blockIdx.x;
    const int qt = blockIdx.y;

    unsigned short* pw = (unsigned short*)(smem + 43008 + wid * 2304);  // per-wave P [16][72]
    unsigned short* tR = (unsigned short*)(smem + wid * 5120);          // transient qR [32][80] (buf0)
    unsigned short* tB = (unsigned short*)(smem + 21504 + wid * 4608);  // transient qbx [32][72] (buf1)

    const int iA = wid * 64 + lane;
    const int ioA = (iA / 5) * 128 + (iA % 5) * 16;
    const int iB = 256 + lane;
    const int ioB = (iB / 5) * 128 + (iB % 5) * 16;

    // ---- prologue: Q frags, qR = q.T^T (log2e-scaled), extended-Q bias frags ----
    bf16x8 a_q0[2], a_q1[2], a_b0[2], a_b1[2];
#pragma unroll
    for (int mt = 0; mt < 2; ++mt) {
        int qrow = qt * 128 + wid * 32 + mt * 16 + l16;
        if (qrow > 1567) qrow = 1567;
        const unsigned short* qp = qb + ((size_t)bh * 1568 + qrow) * 64 + quad * 8;
        a_q0[mt] = ld_bf8(qp);
        a_q1[mt] = ld_bf8(qp + 32);
    }
#pragma unroll
    for (int mt = 0; mt < 2; ++mt) {
#pragma unroll
        for (int ng = 0; ng < 5; ++ng) {
            const unsigned short* tp = Tbf + (size_t)(ng * 16 + l16) * 64 + quad * 8;
            f32x4 t = {};
            t = MFMA16(a_q0[mt], ld_bf8(tp), t);
            t = MFMA16(a_q1[mt], ld_bf8(tp + 32), t);
#pragma unroll
            for (int r = 0; r < 4; ++r)
                tR[(mt * 16 + quad * 4 + r) * 80 + ng * 16 + l16] = f2bf(t[r]);
        }
    }
#pragma unroll
    for (int mt = 0; mt < 2; ++mt) {
        int gq = qt * 128 + wid * 32 + mt * 16 + l16;
        if (gq > 1567) gq = 1567;
        int qd = gq / 196;
        int rm = gq - qd * 196;
        int qh = rm / 14;
        int qw = rm - qh * 14;
        const unsigned short* qr = tR + (mt * 16 + l16) * 80;
        unsigned short* qxr = tB + (mt * 16 + l16) * 72;
#pragma unroll
        for (int t = 0; t < 16; ++t) {
            int dd = quad * 16 + t;
            unsigned short v = 0;
            if (dd < 8)        v = qr[qd - dd + 7];
            else if (dd < 22)  v = qr[15 + qh - (dd - 8) + 13];
            else if (dd < 36)  v = qr[42 + qw - (dd - 22) + 13];
            else if (dd == 36) v = 0xC6EA;  // bf16(-30000): exp2 -> 0 pad-key mask
            qxr[dd] = v;
        }
    }
#pragma unroll
    for (int mt = 0; mt < 2; ++mt) {
        const unsigned short* qx = tB + (mt * 16 + l16) * 72;
        a_b0[mt] = ld_bf8(qx + quad * 8);
        a_b1[mt] = ld_bf8(qx + 32 + quad * 8);
    }
    // CROSS-WAVE hazard: stage() below overwrites other waves' tR/tB regions.
    __syncthreads();

    const char* kbh_b = (const char*)(kb2 + (size_t)bh * 1600 * 64);
    const char* ind_b = (const char*)indb;
    const char* vbh_b = (const char*)(vtb + (size_t)bh * 64 * 1600);

    auto stage = [&](char* sbase, int kb0) {
#pragma unroll
        for (int j = 0; j < 2; ++j) {
            int loc = wid * 16 + j * 8 + sr;
            int gc = ((sc + loc) & 7) * 16;
            dma16(kbh_b + (size_t)(kb0 + loc) * 128 + gc, sbase + (wid * 16 + j * 8) * 128);
            dma16(vbh_b + (size_t)loc * 3200 + (size_t)kb0 * 2 + gc,
                  sbase + 13312 + (wid * 16 + j * 8) * 128);
        }
        dma16(ind_b + (size_t)kb0 * 128 + ioA, sbase + 8192 + wid * 1024);
        if (wid == 0)
            dma16(ind_b + (size_t)kb0 * 128 + ioB, sbase + 8192 + 4096);
    };

    float l_p[2][4] = {};
    f32x4 Oacc[2][4] = {};

    stage(smem, 0);
    __syncthreads();

    for (int kt = 0; kt < 25; ++kt) {
        char* cur = smem + (kt & 1) * 21504;
        if (kt < 24) stage(smem + ((kt + 1) & 1) * 21504, (kt + 1) * 64);

        const unsigned short* sK = (const unsigned short*)cur;
        const unsigned short* sI = (const unsigned short*)(cur + 8192);
        const unsigned short* sV = (const unsigned short*)(cur + 13312);

        float p[2][4][4];
#pragma unroll
        for (int kg = 0; kg < 4; ++kg) {
            int key = kg * 16 + l16;
            const unsigned short* kr = sK + key * 64;
            bf16x8 bk0 = ld_bf8(kr + ((quad - key) & 7) * 8);
            bf16x8 bk1 = ld_bf8(kr + ((quad + 4 - key) & 7) * 8);
            const unsigned short* ir = sI + key * 40;
            bf16x8 bi0 = ld_bf8(ir + quad * 8);
            bf16x8 bi1 = ld_bf8(ir + 32 + quad * 8);
#pragma unroll
            for (int mt = 0; mt < 2; ++mt) {
                f32x4 t = {};
                t = MFMA16(a_q0[mt], bk0, t);
                t = MFMA16(a_q1[mt], bk1, t);
                t = MFMA16(a_b0[mt], bi0, t);
                t = MFMA16(a_b1[mt], bi1, t);
#pragma unroll
                for (int r = 0; r < 4; ++r) {
                    union { float f; unsigned int u; } c;
                    c.f = EXP2(t[r]);
                    c.u &= 0xFFFF0000u;
                    p[mt][kg][r] = c.f;
                    l_p[mt][r] += c.f;
                }
            }
        }
        bf16x8 v0[4], v1[4];
#pragma unroll
        for (int cg = 0; cg < 4; ++cg) {
            int dim = cg * 16 + l16;
            const unsigned short* vr = sV + dim * 64;
            v0[cg] = ld_bf8(vr + ((quad - dim) & 7) * 8);
            v1[cg] = ld_bf8(vr + ((quad + 4 - dim) & 7) * 8);
        }
#pragma unroll
        for (int mt = 0; mt < 2; ++mt) {
#pragma unroll
            for (int kg = 0; kg < 4; ++kg)
#pragma unroll
                for (int r = 0; r < 4; ++r) {
                    union { float f; unsigned int u; } c;
                    c.f = p[mt][kg][r];
                    pw[(quad * 4 + r) * 72 + kg * 16 + l16] = (unsigned short)(c.u >> 16);
                }
            const unsigned short* pr = pw + l16 * 72;
            bf16x8 ap0 = ld_bf8(pr + quad * 8);
            bf16x8 ap1 = ld_bf8(pr + 32 + quad * 8);
#pragma unroll
            for (int cg = 0; cg < 4; ++cg) {
                Oacc[mt][cg] = MFMA16(ap0, v0[cg], Oacc[mt][cg]);
                Oacc[mt][cg] = MFMA16(ap1, v1[cg], Oacc[mt][cg]);
            }
        }
        __syncthreads();
    }

    int b_ = bh / 12;
    int head = bh - b_ * 12;
    unsigned short* ob = obf + (size_t)b_ * 1568 * 768 + head * 64;
#pragma unroll
    for (int mt = 0; mt < 2; ++mt)
#pragma unroll
        for (int r = 0; r < 4; ++r) {
            float v = l_p[mt][r];
            v += __shfl_xor(v, 1);
            v += __shfl_xor(v, 2);
            v += __shfl_xor(v, 4);
            v += __shfl_xor(v, 8);
            int gq = qt * 128 + wid * 32 + mt * 16 + quad * 4 + r;
            if (gq < 1568) {
                float inv = 1.0f / v;
#pragma unroll
                for (int cg = 0; cg < 4; ++cg)
                    ob[(size_t)gq * 768 + cg * 16 + l16] = f2bf(Oacc[mt][cg][r] * inv);
            }
        }
}

// ---------------- GEMM3: out = O @ proj_w + proj_b (fp32 out), 64x128 tiles ----------------
__global__ __launch_bounds__(256, 4) void k_proj(const unsigned short* __restrict__ obf,
                                                 const unsigned short* __restrict__ w2t,
                                                 const float* __restrict__ proj_b,
                                                 float* __restrict__ out) {
    __shared__ __align__(16) char smem[24576];
    f32x4 acc[4][2] = {};
    gemm_core64(obf, w2t, blockIdx.x * 64, blockIdx.y * 128, smem, acc);

    const int lane = threadIdx.x & 63;
    const int wid = threadIdx.x >> 6;
    const int quad = lane >> 4, l16 = lane & 15;
#pragma unroll
    for (int j = 0; j < 2; ++j) {
        int n = blockIdx.y * 128 + wid * 32 + j * 16 + l16;
        float bias = proj_b[n];
#pragma unroll
        for (int i = 0; i < 4; ++i) {
#pragma unroll
            for (int r = 0; r < 4; ++r) {
                int m = blockIdx.x * 64 + i * 16 + quad * 4 + r;
                out[(size_t)m * 768 + n] = acc[i][j][r] + bias;
            }
        }
    }
}

// ---------------- launch ----------------
extern "C" void kernel_launch(void* const* d_in, const int* in_sizes, int n_in,
                              void* d_out, int out_size, void* d_ws, size_t ws_size,
                              hipStream_t stream) {
    const float* x      = (const float*)d_in[0];
    const float* qkv_w  = (const float*)d_in[1];
    const float* qkv_b  = (const float*)d_in[2];
    const float* proj_w = (const float*)d_in[3];
    const float* proj_b = (const float*)d_in[4];
    const float* rd     = (const float*)d_in[5];
    const float* rh     = (const float*)d_in[6];
    const float* rw     = (const float*)d_in[7];
    float* out = (float*)d_out;

    char* ws = (char*)d_ws;
    size_t off = 0;
    auto alloc = [&](size_t bytes) {
        char* p = ws + off;
        off += (bytes + 255) & ~(size_t)255;
        return p;
    };
    unsigned short* xbf  = (unsigned short*)alloc((size_t)6272 * 768 * 2);   // reused as obf
    unsigned short* w1t  = (unsigned short*)alloc((size_t)2304 * 768 * 2);
    unsigned short* w2t  = (unsigned short*)alloc((size_t)768 * 768 * 2);
    unsigned short* Tbf  = (unsigned short*)alloc((size_t)80 * 64 * 2);
    unsigned short* qb   = (unsigned short*)alloc((size_t)48 * 1568 * 64 * 2);
    unsigned short* kb2  = (unsigned short*)alloc((size_t)48 * 1600 * 64 * 2);
    unsigned short* vtb  = (unsigned short*)alloc((size_t)48 * 64 * 1600 * 2);
    unsigned short* indb = (unsigned short*)alloc((size_t)1600 * 64 * 2);
    unsigned short* obf  = xbf;                 // x dead after k_qkv

    hipLaunchKernelGGL(k_prep, dim3(5700), dim3(256), 0, stream,
                       x, xbf, qkv_w, w1t, proj_w, w2t, rd, rh, rw, Tbf, indb);
    hipLaunchKernelGGL(k_qkv, dim3(49, 18), dim3(256), 0, stream, xbf, w1t, qkv_b, qb, kb2, vtb);
    hipLaunchKernelGGL(k_attn, dim3(48, 13), dim3(256), 0, stream, qb, kb2, indb, vtb, Tbf, obf);
    hipLaunchKernelGGL(k_proj, dim3(98, 6), dim3(256), 0, stream, obf, w2t, proj_b, out);
}